// Round 1
// baseline (697.271 us; speedup 1.0000x reference)
//
#include <hip/hip_runtime.h>

#define NB 8
#define NC 16
#define NH 256
#define NW 256
#define TS 16
#define ALIVE_THRESH 0.1f
#define UPDATE_RATE 0.25f

// ---------------------------------------------------------------------------
// Kernel A: per step — perceive (depthwise ident/sobelx/sobely), MLP,
// stochastic update, pre-alive mask.
//   x_mid = x + mlp(perceive(x)) * (um < 0.25)
//   pre   = (3x3 wrap-max of x alpha) > 0.1
// ---------------------------------------------------------------------------
__global__ __launch_bounds__(256) void nca_step_a(
    const float* __restrict__ x,
    const float* __restrict__ w1, const float* __restrict__ b1,
    const float* __restrict__ w2, const float* __restrict__ b2,
    const float* __restrict__ w3,
    const float* __restrict__ um,      // already offset to step i: (B,1,H,W)
    float* __restrict__ xmid,
    float* __restrict__ pre)
{
    // halo tile: 16 channels x (16+2) rows x (16+2) cols, col-padded to 20
    __shared__ float tile[NC][TS + 2][TS + 4];

    const int tx = threadIdx.x, ty = threadIdx.y;
    const int tid = ty * TS + tx;
    const int w0 = blockIdx.x * TS, h0 = blockIdx.y * TS;
    const int b = blockIdx.z;

    // cooperative halo load with wrap (H, W are powers of 2)
    const int tile_elems = NC * (TS + 2) * (TS + 2);
    for (int idx = tid; idx < tile_elems; idx += 256) {
        int c   = idx / ((TS + 2) * (TS + 2));
        int rem = idx - c * ((TS + 2) * (TS + 2));
        int r   = rem / (TS + 2);
        int col = rem - r * (TS + 2);
        int hh = (h0 + r   - 1) & (NH - 1);
        int ww = (w0 + col - 1) & (NW - 1);
        tile[c][r][col] = x[(((size_t)b * NC + c) * NH + hh) * NW + ww];
    }
    __syncthreads();

    // perceive: y[3c]=ident, y[3c+1]=sobel_x, y[3c+2]=sobel_y (cross-corr, no flip)
    float y[3 * NC];
    #pragma unroll
    for (int c = 0; c < NC; ++c) {
        float a00 = tile[c][ty + 0][tx + 0], a01 = tile[c][ty + 0][tx + 1], a02 = tile[c][ty + 0][tx + 2];
        float a10 = tile[c][ty + 1][tx + 0], a11 = tile[c][ty + 1][tx + 1], a12 = tile[c][ty + 1][tx + 2];
        float a20 = tile[c][ty + 2][tx + 0], a21 = tile[c][ty + 2][tx + 1], a22 = tile[c][ty + 2][tx + 2];
        y[3 * c + 0] = a11;
        // sx = [[-1,0,1],[-2,0,2],[-1,0,1]]
        y[3 * c + 1] = (a02 - a00) + 2.0f * (a12 - a10) + (a22 - a20);
        // sy = sx.T = [[-1,-2,-1],[0,0,0],[1,2,1]]
        y[3 * c + 2] = (a20 - a00) + 2.0f * (a21 - a01) + (a22 - a02);
    }

    // pre-alive mask from channel 3 neighborhood (same LDS tile)
    float mx = -1e30f;
    #pragma unroll
    for (int dy = 0; dy < 3; ++dy)
        #pragma unroll
        for (int dx = 0; dx < 3; ++dx)
            mx = fmaxf(mx, tile[3][ty + dy][tx + dx]);
    const float pre_v = (mx > ALIVE_THRESH) ? 1.0f : 0.0f;

    // MLP layer 1: 48 -> 64, relu.  Weight loads are wave-uniform -> s_load.
    float h1[64];
    #pragma unroll
    for (int o = 0; o < 64; ++o) {
        float acc = b1[o];
        #pragma unroll
        for (int c = 0; c < 48; ++c)
            acc = fmaf(w1[o * 48 + c], y[c], acc);
        h1[o] = fmaxf(acc, 0.0f);
    }

    // MLP layer 2: 64 -> 64, relu
    float h2[64];
    #pragma unroll
    for (int o = 0; o < 64; ++o) {
        float acc = b2[o];
        #pragma unroll
        for (int c = 0; c < 64; ++c)
            acc = fmaf(w2[o * 64 + c], h1[c], acc);
        h2[o] = fmaxf(acc, 0.0f);
    }

    // MLP layer 3: 64 -> 16 (no bias, no relu) + stochastic update + store
    const int h = h0 + ty, w = w0 + tx;
    const size_t pix = ((size_t)b * NH + h) * NW + w;
    const float um_v = (um[pix] < UPDATE_RATE) ? 1.0f : 0.0f;
    pre[pix] = pre_v;

    #pragma unroll
    for (int c = 0; c < NC; ++c) {
        float acc = 0.0f;
        #pragma unroll
        for (int o = 0; o < 64; ++o)
            acc = fmaf(w3[c * 64 + o], h2[o], acc);
        xmid[(((size_t)b * NC + c) * NH + h) * NW + w] =
            tile[c][ty + 1][tx + 1] + acc * um_v;
    }
}

// ---------------------------------------------------------------------------
// Kernel B: post-alive mask on updated state, apply pre*post.
//   post  = (3x3 wrap-max of x_mid alpha) > 0.1
//   x_out = x_mid * pre * post
// ---------------------------------------------------------------------------
__global__ __launch_bounds__(256) void nca_step_b(
    const float* __restrict__ xmid,
    const float* __restrict__ pre,
    float* __restrict__ xout)
{
    const int gid = blockIdx.x * 256 + threadIdx.x;   // over B*H*W
    const int b   = gid >> 16;                        // H*W = 65536
    const int rem = gid & 65535;
    const int h   = rem >> 8;
    const int w   = rem & 255;

    const float* alpha = xmid + (((size_t)b * NC + 3) * NH) * NW;
    float mx = -1e30f;
    #pragma unroll
    for (int dy = -1; dy <= 1; ++dy) {
        const int hh = (h + dy) & (NH - 1);
        #pragma unroll
        for (int dx = -1; dx <= 1; ++dx) {
            const int ww = (w + dx) & (NW - 1);
            mx = fmaxf(mx, alpha[hh * NW + ww]);
        }
    }
    const float post = (mx > ALIVE_THRESH) ? 1.0f : 0.0f;
    const float m = post * pre[gid];

    #pragma unroll
    for (int c = 0; c < NC; ++c) {
        const size_t o = (((size_t)b * NC + c) * NH + h) * NW + w;
        xout[o] = xmid[o] * m;
    }
}

// ---------------------------------------------------------------------------
extern "C" void kernel_launch(void* const* d_in, const int* in_sizes, int n_in,
                              void* d_out, int out_size, void* d_ws, size_t ws_size,
                              hipStream_t stream) {
    const float* x  = (const float*)d_in[0];
    const float* w1 = (const float*)d_in[1];
    const float* b1 = (const float*)d_in[2];
    const float* w2 = (const float*)d_in[3];
    const float* b2 = (const float*)d_in[4];
    const float* w3 = (const float*)d_in[5];
    const float* um = (const float*)d_in[6];
    const int steps = in_sizes[6] / (NB * NH * NW);   // update_masks: (steps,B,1,H,W)

    float* xmid = (float*)d_ws;                        // B*C*H*W floats (32 MB)
    float* pre  = xmid + (size_t)NB * NC * NH * NW;    // B*H*W floats (2 MB)
    float* xout = (float*)d_out;

    dim3 blkA(TS, TS);
    dim3 grdA(NW / TS, NH / TS, NB);
    const int grdB = (NB * NH * NW) / 256;

    const float* cur = x;
    for (int i = 0; i < steps; ++i) {
        nca_step_a<<<grdA, blkA, 0, stream>>>(cur, w1, b1, w2, b2, w3,
                                              um + (size_t)i * NB * NH * NW,
                                              xmid, pre);
        nca_step_b<<<grdB, 256, 0, stream>>>(xmid, pre, xout);
        cur = xout;   // next step reads the just-written state
    }
}

// Round 2
// 87.421 us; speedup vs baseline: 7.9760x; 7.9760x over previous
//
#include <hip/hip_runtime.h>

#define NB 8
#define NC 16
#define NH 256
#define NW 256
#define ALIVE_THRESH 0.1f
#define UPDATE_RATE 0.25f

typedef __attribute__((ext_vector_type(8))) short bf16x8;
typedef __attribute__((ext_vector_type(4))) float f32x4;

#define MFMA16(a, b, c) __builtin_amdgcn_mfma_f32_16x16x32_bf16((a), (b), (c), 0, 0, 0)

static __device__ __forceinline__ unsigned short f2bf(float f) {
    union { float f; unsigned u; } x; x.f = f;
    unsigned r = x.u + 0x7FFFu + ((x.u >> 16) & 1u);   // RNE
    return (unsigned short)(r >> 16);
}
static __device__ __forceinline__ float bf2f(unsigned short b) {
    union { unsigned u; float f; } x; x.u = ((unsigned)b) << 16; return x.f;
}

// swizzled byte offset into the [256 px][64 bf16] activation buffer
// (row stride 128B, XOR 16B-granule index with px&7 -> bank-conflict-free)
static __device__ __forceinline__ int ybyte(int px, int g) {
    return px * 128 + ((g ^ (px & 7)) << 4);
}

// ---------------------------------------------------------------------------
// Pre-kernel: pack W1(+b1 as k=48 row), W2, W3 into MFMA A-fragment order.
// frag f, lane l -> 8 bf16 (int4).  f<8: L1 (mt*2+ks); f<16: L2; f<18: L3.
// A-layout for mfma_f32_16x16x32_bf16: lane l holds A[m = base_m + (l&15)]
// [k = ks*32 + (l>>4)*8 + j], j=0..7.
// ---------------------------------------------------------------------------
__global__ void prep_weights(const float* __restrict__ w1, const float* __restrict__ b1,
                             const float* __restrict__ w2, const float* __restrict__ w3,
                             int4* __restrict__ wf)
{
    const int f = blockIdx.x, l = threadIdx.x;
    const int lq = l >> 4, ln = l & 15;
    union { unsigned short us[8]; int4 v; } u;
    if (f < 8) {
        const int mt = f >> 1, ks = f & 1, m = mt * 16 + ln;
        #pragma unroll
        for (int j = 0; j < 8; ++j) {
            const int k = ks * 32 + lq * 8 + j;
            float v = (k < 48) ? w1[m * 48 + k] : ((k == 48) ? b1[m] : 0.0f);
            u.us[j] = f2bf(v);
        }
    } else if (f < 16) {
        const int ff = f - 8, mt = ff >> 1, ks = ff & 1, m = mt * 16 + ln;
        #pragma unroll
        for (int j = 0; j < 8; ++j) {
            const int k = ks * 32 + lq * 8 + j;
            u.us[j] = f2bf(w2[m * 64 + k]);
        }
    } else {
        const int ks = f - 16, m = ln;
        #pragma unroll
        for (int j = 0; j < 8; ++j) {
            const int k = ks * 32 + lq * 8 + j;
            u.us[j] = f2bf(w3[m * 64 + k]);
        }
    }
    wf[f * 64 + l] = u.v;
}

// ---------------------------------------------------------------------------
// Kernel A: one block = one image row (b, h). 256 threads = 4 waves.
//  phase 1: perceive via separable sobel (s = top+2mid+bot, d = bot-top),
//           pre-alive col-max; one barrier.
//  phase 2: y -> bf16 [px][64] LDS (k=48 is constant-1 for the L1 bias).
//  phase 3: per wave (64 own px): L1/L2/L3 MFMA GEMMs, h1/h2 in-place,
//           epilogue xmid = x + y*um.
// ---------------------------------------------------------------------------
__global__ __launch_bounds__(256) void nca_step_a(
    const float* __restrict__ x,
    const float* __restrict__ um,      // offset to step i: (B,1,H,W)
    const float* __restrict__ b2,
    const int4*  __restrict__ wf,
    float* __restrict__ xmid,
    unsigned char* __restrict__ preb)
{
    __shared__ char      ybuf[256 * 128];   // 32 KB
    __shared__ unsigned  sd[NC][NW];        // 16 KB (bf16 s | bf16 d << 16)
    __shared__ float     premax[NW];        // 1 KB

    const int t = threadIdx.x;
    const int bx = blockIdx.x;
    const int h = ((bx & 7) << 5) | (bx >> 3);   // XCD-chunked row swizzle
    const int b = blockIdx.y;
    const int hm = (h - 1) & (NH - 1), hp = (h + 1) & (NH - 1);
    const size_t base = (size_t)b * NC * NH * NW;

    // ---- phase 1: column loads + vertical smooth/diff --------------------
    float dreg[NC], mreg[NC];
    #pragma unroll
    for (int c = 0; c < NC; ++c) {
        const float* xc = x + base + (size_t)c * NH * NW;
        float top = xc[hm * NW + t];
        float mid = xc[h  * NW + t];
        float bot = xc[hp * NW + t];
        float s = top + 2.0f * mid + bot;
        float d = bot - top;
        sd[c][t] = (unsigned)f2bf(s) | ((unsigned)f2bf(d) << 16);
        dreg[c] = d; mreg[c] = mid;
        if (c == 3) premax[t] = fmaxf(fmaxf(top, mid), bot);
    }
    __syncthreads();

    // ---- pre-alive mask (byte) -------------------------------------------
    {
        float m0 = premax[(t - 1) & (NW - 1)];
        float m1 = premax[t];
        float m2 = premax[(t + 1) & (NW - 1)];
        float mx = fmaxf(fmaxf(m0, m1), m2);
        preb[((size_t)b * NH + h) * NW + t] = (mx > ALIVE_THRESH) ? 1 : 0;
    }

    // ---- phase 2: horizontal combine -> y[48] bf16 packed ----------------
    {
        unsigned yp[24];
        #pragma unroll
        for (int c = 0; c < NC; ++c) {
            unsigned L = sd[c][(t - 1) & (NW - 1)];
            unsigned R = sd[c][(t + 1) & (NW - 1)];
            float sl = bf2f((unsigned short)L), dl = bf2f((unsigned short)(L >> 16));
            float sr = bf2f((unsigned short)R), dr = bf2f((unsigned short)(R >> 16));
            float y0 = mreg[c];                       // ident
            float y1 = sr - sl;                       // sobel_x
            float y2 = dl + 2.0f * dreg[c] + dr;      // sobel_y
            unsigned short u[3] = { f2bf(y0), f2bf(y1), f2bf(y2) };
            #pragma unroll
            for (int q = 0; q < 3; ++q) {
                const int k = 3 * c + q;
                if ((k & 1) == 0) yp[k >> 1]  = u[q];
                else              yp[k >> 1] |= ((unsigned)u[q]) << 16;
            }
        }
        char* yb = (char*)ybuf;
        #pragma unroll
        for (int g = 0; g < 6; ++g) {
            union { unsigned w[4]; int4 v; } pk;
            pk.w[0] = yp[4 * g]; pk.w[1] = yp[4 * g + 1];
            pk.w[2] = yp[4 * g + 2]; pk.w[3] = yp[4 * g + 3];
            *(int4*)(yb + ybyte(t, g)) = pk.v;
        }
        int4 biasrow; biasrow.x = 0x3F80; biasrow.y = 0; biasrow.z = 0; biasrow.w = 0;
        *(int4*)(yb + ybyte(t, 6)) = biasrow;         // k=48 -> 1.0 (bias)
        int4 zz; zz.x = zz.y = zz.z = zz.w = 0;
        *(int4*)(yb + ybyte(t, 7)) = zz;              // k=56..63 -> 0
    }
    // No barrier: each wave's MFMA B-reads only touch rows px written by
    // its own lanes (px in [wv*64, wv*64+64)) — intra-wave, in-order LDS.

    // ---- phase 3: GEMMs ----------------------------------------------------
    char* yb = (char*)ybuf;
    const int lane = t & 63, wv = t >> 6;
    const int lq = lane >> 4, ln = lane & 15;
    const int px0 = wv * 64;

    // um -> 0/1 per N-tile
    float umv[4];
    {
        const float* umr = um + ((size_t)b * NH + h) * NW;
        #pragma unroll
        for (int nt = 0; nt < 4; ++nt)
            umv[nt] = (umr[px0 + nt * 16 + ln] < UPDATE_RATE) ? 1.0f : 0.0f;
    }

    // ---- L1: 64 <- 48(+bias), relu; h1 written in place -------------------
    bf16x8 a1[8];
    #pragma unroll
    for (int f = 0; f < 8; ++f) a1[f] = __builtin_bit_cast(bf16x8, wf[f * 64 + lane]);

    #pragma unroll
    for (int nt = 0; nt < 4; ++nt) {
        const int px = px0 + nt * 16 + ln;
        bf16x8 bb0 = *(const bf16x8*)(yb + ybyte(px, lq));
        bf16x8 bb1 = *(const bf16x8*)(yb + ybyte(px, 4 + lq));
        f32x4 acc[4];
        #pragma unroll
        for (int mt = 0; mt < 4; ++mt) {
            f32x4 z = {0.f, 0.f, 0.f, 0.f};
            z = MFMA16(a1[2 * mt],     bb0, z);
            z = MFMA16(a1[2 * mt + 1], bb1, z);
            acc[mt] = z;
        }
        #pragma unroll
        for (int mt = 0; mt < 4; ++mt) {
            unsigned p0 = (unsigned)f2bf(fmaxf(acc[mt][0], 0.f)) |
                          ((unsigned)f2bf(fmaxf(acc[mt][1], 0.f)) << 16);
            unsigned p1 = (unsigned)f2bf(fmaxf(acc[mt][2], 0.f)) |
                          ((unsigned)f2bf(fmaxf(acc[mt][3], 0.f)) << 16);
            union { unsigned w[2]; uint2 v; } pk; pk.w[0] = p0; pk.w[1] = p1;
            *(uint2*)(yb + ybyte(px, 2 * mt + (lq >> 1)) + (lq & 1) * 8) = pk.v;
        }
    }

    // ---- L2: 64 <- 64, +b2, relu; h2 in place ------------------------------
    bf16x8 a2[8];
    #pragma unroll
    for (int f = 0; f < 8; ++f) a2[f] = __builtin_bit_cast(bf16x8, wf[(8 + f) * 64 + lane]);
    f32x4 b2v[4];
    #pragma unroll
    for (int mt = 0; mt < 4; ++mt)
        b2v[mt] = *(const f32x4*)(b2 + mt * 16 + lq * 4);

    #pragma unroll
    for (int nt = 0; nt < 4; ++nt) {
        const int px = px0 + nt * 16 + ln;
        bf16x8 bb0 = *(const bf16x8*)(yb + ybyte(px, lq));
        bf16x8 bb1 = *(const bf16x8*)(yb + ybyte(px, 4 + lq));
        f32x4 acc[4];
        #pragma unroll
        for (int mt = 0; mt < 4; ++mt) {
            f32x4 z = {0.f, 0.f, 0.f, 0.f};
            z = MFMA16(a2[2 * mt],     bb0, z);
            z = MFMA16(a2[2 * mt + 1], bb1, z);
            acc[mt] = z + b2v[mt];
        }
        #pragma unroll
        for (int mt = 0; mt < 4; ++mt) {
            unsigned p0 = (unsigned)f2bf(fmaxf(acc[mt][0], 0.f)) |
                          ((unsigned)f2bf(fmaxf(acc[mt][1], 0.f)) << 16);
            unsigned p1 = (unsigned)f2bf(fmaxf(acc[mt][2], 0.f)) |
                          ((unsigned)f2bf(fmaxf(acc[mt][3], 0.f)) << 16);
            union { unsigned w[2]; uint2 v; } pk; pk.w[0] = p0; pk.w[1] = p1;
            *(uint2*)(yb + ybyte(px, 2 * mt + (lq >> 1)) + (lq & 1) * 8) = pk.v;
        }
    }

    // ---- L3: 16 <- 64 + epilogue ------------------------------------------
    bf16x8 a3[2];
    a3[0] = __builtin_bit_cast(bf16x8, wf[16 * 64 + lane]);
    a3[1] = __builtin_bit_cast(bf16x8, wf[17 * 64 + lane]);

    #pragma unroll
    for (int nt = 0; nt < 4; ++nt) {
        const int px = px0 + nt * 16 + ln;
        float xcv[4];
        #pragma unroll
        for (int r = 0; r < 4; ++r)
            xcv[r] = x[base + (size_t)(lq * 4 + r) * (NH * NW) + h * NW + px];
        bf16x8 bb0 = *(const bf16x8*)(yb + ybyte(px, lq));
        bf16x8 bb1 = *(const bf16x8*)(yb + ybyte(px, 4 + lq));
        f32x4 z = {0.f, 0.f, 0.f, 0.f};
        z = MFMA16(a3[0], bb0, z);
        z = MFMA16(a3[1], bb1, z);
        #pragma unroll
        for (int r = 0; r < 4; ++r)
            xmid[base + (size_t)(lq * 4 + r) * (NH * NW) + h * NW + px] =
                xcv[r] + z[r] * umv[nt];
    }
}

// ---------------------------------------------------------------------------
// Kernel B: post-alive on xmid, apply pre*post. 4 px per thread (float4).
// ---------------------------------------------------------------------------
__global__ __launch_bounds__(256) void nca_step_b(
    const float* __restrict__ xmid,
    const unsigned char* __restrict__ preb,
    float* __restrict__ xout)
{
    const int gid = blockIdx.x * 256 + threadIdx.x;     // over B*H*(W/4)
    const int b   = gid >> 14;                          // H*W/4 = 16384
    const int rem = gid & 16383;
    const int h   = rem >> 6;
    const int px  = (rem & 63) << 2;

    const float* alpha = xmid + ((size_t)b * NC + 3) * NH * NW;
    float m0 = -1e30f, m1 = -1e30f, m2 = -1e30f, m3 = -1e30f;
    #pragma unroll
    for (int dy = -1; dy <= 1; ++dy) {
        const int row = (h + dy) & (NH - 1);
        const float* r = alpha + row * NW;
        float4 mid4 = *(const float4*)(r + px);
        float lm = r[(px - 1) & (NW - 1)];
        float rm = r[(px + 4) & (NW - 1)];
        m0 = fmaxf(m0, fmaxf(fmaxf(lm, mid4.x), mid4.y));
        m1 = fmaxf(m1, fmaxf(fmaxf(mid4.x, mid4.y), mid4.z));
        m2 = fmaxf(m2, fmaxf(fmaxf(mid4.y, mid4.z), mid4.w));
        m3 = fmaxf(m3, fmaxf(fmaxf(mid4.z, mid4.w), rm));
    }
    const size_t pix = ((size_t)b * NH + h) * NW + px;
    const unsigned char* pr = preb + pix;
    float f0 = (m0 > ALIVE_THRESH && pr[0]) ? 1.0f : 0.0f;
    float f1 = (m1 > ALIVE_THRESH && pr[1]) ? 1.0f : 0.0f;
    float f2 = (m2 > ALIVE_THRESH && pr[2]) ? 1.0f : 0.0f;
    float f3 = (m3 > ALIVE_THRESH && pr[3]) ? 1.0f : 0.0f;

    #pragma unroll
    for (int c = 0; c < NC; ++c) {
        const size_t o = (((size_t)b * NC + c) * NH + h) * NW + px;
        float4 v = *(const float4*)(xmid + o);
        v.x *= f0; v.y *= f1; v.z *= f2; v.w *= f3;
        *(float4*)(xout + o) = v;
    }
}

// ---------------------------------------------------------------------------
extern "C" void kernel_launch(void* const* d_in, const int* in_sizes, int n_in,
                              void* d_out, int out_size, void* d_ws, size_t ws_size,
                              hipStream_t stream) {
    const float* x  = (const float*)d_in[0];
    const float* w1 = (const float*)d_in[1];
    const float* b1 = (const float*)d_in[2];
    const float* w2 = (const float*)d_in[3];
    const float* b2 = (const float*)d_in[4];
    const float* w3 = (const float*)d_in[5];
    const float* um = (const float*)d_in[6];
    const int steps = in_sizes[6] / (NB * NH * NW);

    float* xmid         = (float*)d_ws;                         // 32 MB
    unsigned char* preb = (unsigned char*)(xmid + (size_t)NB * NC * NH * NW); // 512 KB
    int4* wf            = (int4*)(preb + (size_t)NB * NH * NW); // 18 KB
    float* xout         = (float*)d_out;

    prep_weights<<<18, 64, 0, stream>>>(w1, b1, w2, w3, wf);

    dim3 grdA(NH, NB);
    const int grdB = (NB * NH * NW / 4) / 256;

    const float* cur = x;
    for (int i = 0; i < steps; ++i) {
        nca_step_a<<<grdA, 256, 0, stream>>>(cur,
                                             um + (size_t)i * NB * NH * NW,
                                             b2, wf, xmid, preb);
        nca_step_b<<<grdB, 256, 0, stream>>>(xmid, preb, xout);
        cur = xout;
    }
}

// Round 3
// 76.467 us; speedup vs baseline: 9.1186x; 1.1433x over previous
//
#include <hip/hip_runtime.h>

#define NB 8
#define NC 16
#define NH 256
#define NW 256
#define ALIVE_THRESH 0.1f
#define UPDATE_RATE 0.25f

typedef __attribute__((ext_vector_type(8))) short bf16x8;
typedef __attribute__((ext_vector_type(4))) float f32x4;
typedef unsigned short ushort_t;

#define MFMA16(a, b, c) __builtin_amdgcn_mfma_f32_16x16x32_bf16((a), (b), (c), 0, 0, 0)

static __device__ __forceinline__ unsigned short f2bf(float f) {
    union { float f; unsigned u; } x; x.f = f;
    unsigned r = x.u + 0x7FFFu + ((x.u >> 16) & 1u);   // RNE
    return (unsigned short)(r >> 16);
}
static __device__ __forceinline__ float bf2f(unsigned short b) {
    union { unsigned u; float f; } x; x.u = ((unsigned)b) << 16; return x.f;
}

// swizzled byte offset into the [256 px][64 bf16] activation buffer
static __device__ __forceinline__ int ybyte(int px, int g) {
    return px * 128 + ((g ^ (px & 7)) << 4);
}

// ---------------------------------------------------------------------------
// Pre-kernel: pack W1(+b1 as k=48 row), W2, W3 into MFMA A-fragment order.
// ---------------------------------------------------------------------------
__global__ void prep_weights(const float* __restrict__ w1, const float* __restrict__ b1,
                             const float* __restrict__ w2, const float* __restrict__ w3,
                             int4* __restrict__ wf)
{
    const int f = blockIdx.x, l = threadIdx.x;
    const int lq = l >> 4, ln = l & 15;
    union { unsigned short us[8]; int4 v; } u;
    if (f < 8) {
        const int mt = f >> 1, ks = f & 1, m = mt * 16 + ln;
        #pragma unroll
        for (int j = 0; j < 8; ++j) {
            const int k = ks * 32 + lq * 8 + j;
            float v = (k < 48) ? w1[m * 48 + k] : ((k == 48) ? b1[m] : 0.0f);
            u.us[j] = f2bf(v);
        }
    } else if (f < 16) {
        const int ff = f - 8, mt = ff >> 1, ks = ff & 1, m = mt * 16 + ln;
        #pragma unroll
        for (int j = 0; j < 8; ++j)
            u.us[j] = f2bf(w2[m * 64 + (ks * 32 + lq * 8 + j)]);
    } else {
        const int ks = f - 16, m = ln;
        #pragma unroll
        for (int j = 0; j < 8; ++j)
            u.us[j] = f2bf(w3[m * 64 + (ks * 32 + lq * 8 + j)]);
    }
    wf[f * 64 + l] = u.v;
}

// ---------------------------------------------------------------------------
// Kernel A: one block = one image row (b,h). 4 waves.
// MASK_IN:  input is bf16 unmasked xmid of previous step; apply pre*post on
//           the fly (5-row alpha window) and emit pre of THIS step.
// !MASK_IN: input is f32 state (first step).
// OUT_BF16: store updated (unmasked) state as bf16, else f32.
// ---------------------------------------------------------------------------
template<bool MASK_IN, bool OUT_BF16>
__global__ __launch_bounds__(256) void nca_step_a(
    const void* __restrict__ xin_v,
    const float* __restrict__ um,      // offset to this step: (B,1,H,W)
    const float* __restrict__ b2,
    const int4*  __restrict__ wf,
    void* __restrict__ xout_v,
    const unsigned char* __restrict__ preb_in,
    unsigned char* __restrict__ preb_out)
{
    __shared__ char      ybuf[256 * 128];   // 32 KB (vbuf overlaid at start)
    __shared__ unsigned  sd[NC][NW];        // 16 KB (bf16 s | bf16 d << 16)
    __shared__ float     premax2[NW];       // 1 KB: vertical alpha max (masked)
    __shared__ float     mmid[NW];          // 1 KB: mid-row mask (MASK_IN only)

    const int t = threadIdx.x;
    const int bx = blockIdx.x;
    const int h = ((bx & 7) << 5) | (bx >> 3);   // XCD-chunked row swizzle
    const int b = blockIdx.y;
    const int hm = (h - 1) & (NH - 1), hp = (h + 1) & (NH - 1);
    const size_t cs = (size_t)NH * NW;
    const size_t base = (size_t)b * NC * cs;

    float mreg[NC], dreg[NC];

    if constexpr (MASK_IN) {
        const ushort_t* xin = (const ushort_t*)xin_v;
        float* vbuf = (float*)ybuf;              // [3][NW], dead before phase2
        const ushort_t* ac = xin + base + 3 * cs;
        float am[5];
        #pragma unroll
        for (int j = 0; j < 5; ++j)
            am[j] = bf2f(ac[(size_t)((h - 2 + j) & (NH - 1)) * NW + t]);
        vbuf[0 * NW + t] = fmaxf(fmaxf(am[0], am[1]), am[2]);
        vbuf[1 * NW + t] = fmaxf(fmaxf(am[1], am[2]), am[3]);
        vbuf[2 * NW + t] = fmaxf(fmaxf(am[2], am[3]), am[4]);
        const unsigned char p0 = preb_in[((size_t)b * NH + hm) * NW + t];
        const unsigned char p1 = preb_in[((size_t)b * NH + h ) * NW + t];
        const unsigned char p2 = preb_in[((size_t)b * NH + hp) * NW + t];
        __syncthreads();

        const int tm = (t - 1) & (NW - 1), tp = (t + 1) & (NW - 1);
        float x0 = fmaxf(fmaxf(vbuf[tm],           vbuf[t]),           vbuf[tp]);
        float x1 = fmaxf(fmaxf(vbuf[NW + tm],      vbuf[NW + t]),      vbuf[NW + tp]);
        float x2 = fmaxf(fmaxf(vbuf[2 * NW + tm],  vbuf[2 * NW + t]),  vbuf[2 * NW + tp]);
        const float m0 = (x0 > ALIVE_THRESH && p0) ? 1.0f : 0.0f;
        const float m1 = (x1 > ALIVE_THRESH && p1) ? 1.0f : 0.0f;
        const float m2 = (x2 > ALIVE_THRESH && p2) ? 1.0f : 0.0f;
        mmid[t] = m1;
        premax2[t] = fmaxf(fmaxf(am[1] * m0, am[2] * m1), am[3] * m2);

        #pragma unroll
        for (int c = 0; c < NC; ++c) {
            float top, mid, bot;
            if (c == 3) { top = am[1] * m0; mid = am[2] * m1; bot = am[3] * m2; }
            else {
                const ushort_t* xc = xin + base + (size_t)c * cs;
                top = bf2f(xc[(size_t)hm * NW + t]) * m0;
                mid = bf2f(xc[(size_t)h  * NW + t]) * m1;
                bot = bf2f(xc[(size_t)hp * NW + t]) * m2;
            }
            float s = top + 2.0f * mid + bot, d = bot - top;
            sd[c][t] = (unsigned)f2bf(s) | ((unsigned)f2bf(d) << 16);
            mreg[c] = mid; dreg[c] = d;
        }
        __syncthreads();
    } else {
        const float* xin = (const float*)xin_v;
        #pragma unroll
        for (int c = 0; c < NC; ++c) {
            const float* xc = xin + base + (size_t)c * cs;
            float top = xc[(size_t)hm * NW + t];
            float mid = xc[(size_t)h  * NW + t];
            float bot = xc[(size_t)hp * NW + t];
            float s = top + 2.0f * mid + bot, d = bot - top;
            sd[c][t] = (unsigned)f2bf(s) | ((unsigned)f2bf(d) << 16);
            mreg[c] = mid; dreg[c] = d;
            if (c == 3) premax2[t] = fmaxf(fmaxf(top, mid), bot);
        }
        __syncthreads();
    }

    // ---- pre mask of THIS step (alive of masked input state) --------------
    {
        const int tm = (t - 1) & (NW - 1), tp = (t + 1) & (NW - 1);
        float mx = fmaxf(fmaxf(premax2[tm], premax2[t]), premax2[tp]);
        preb_out[((size_t)b * NH + h) * NW + t] = (mx > ALIVE_THRESH) ? 1 : 0;
    }

    // ---- phase 2: horizontal combine -> y[48] bf16 packed ------------------
    {
        unsigned yp[24];
        #pragma unroll
        for (int c = 0; c < NC; ++c) {
            unsigned L = sd[c][(t - 1) & (NW - 1)];
            unsigned R = sd[c][(t + 1) & (NW - 1)];
            float sl = bf2f((unsigned short)L), dl = bf2f((unsigned short)(L >> 16));
            float sr = bf2f((unsigned short)R), dr = bf2f((unsigned short)(R >> 16));
            float y0 = mreg[c];                       // ident
            float y1 = sr - sl;                       // sobel_x
            float y2 = dl + 2.0f * dreg[c] + dr;      // sobel_y
            unsigned short u[3] = { f2bf(y0), f2bf(y1), f2bf(y2) };
            #pragma unroll
            for (int q = 0; q < 3; ++q) {
                const int k = 3 * c + q;
                if ((k & 1) == 0) yp[k >> 1]  = u[q];
                else              yp[k >> 1] |= ((unsigned)u[q]) << 16;
            }
        }
        char* yb = (char*)ybuf;
        #pragma unroll
        for (int g = 0; g < 6; ++g) {
            union { unsigned w[4]; int4 v; } pk;
            pk.w[0] = yp[4 * g]; pk.w[1] = yp[4 * g + 1];
            pk.w[2] = yp[4 * g + 2]; pk.w[3] = yp[4 * g + 3];
            *(int4*)(yb + ybyte(t, g)) = pk.v;
        }
        int4 biasrow; biasrow.x = 0x3F80; biasrow.y = 0; biasrow.z = 0; biasrow.w = 0;
        *(int4*)(yb + ybyte(t, 6)) = biasrow;         // k=48 -> 1.0 (bias)
        int4 zz; zz.x = zz.y = zz.z = zz.w = 0;
        *(int4*)(yb + ybyte(t, 7)) = zz;
    }
    // No barrier: each wave's MFMA B-reads only touch px rows written by its
    // own lanes.

    // ---- phase 3: GEMMs -----------------------------------------------------
    char* yb = (char*)ybuf;
    const int lane = t & 63, wv = t >> 6;
    const int lq = lane >> 4, ln = lane & 15;
    const int px0 = wv * 64;

    float umv[4];
    {
        const float* umr = um + ((size_t)b * NH + h) * NW;
        #pragma unroll
        for (int nt = 0; nt < 4; ++nt)
            umv[nt] = (umr[px0 + nt * 16 + ln] < UPDATE_RATE) ? 1.0f : 0.0f;
    }

    // ---- L1: 64 <- 48(+bias), relu; h1 in place ----------------------------
    bf16x8 a1[8];
    #pragma unroll
    for (int f = 0; f < 8; ++f) a1[f] = __builtin_bit_cast(bf16x8, wf[f * 64 + lane]);

    #pragma unroll
    for (int nt = 0; nt < 4; ++nt) {
        const int px = px0 + nt * 16 + ln;
        bf16x8 bb0 = *(const bf16x8*)(yb + ybyte(px, lq));
        bf16x8 bb1 = *(const bf16x8*)(yb + ybyte(px, 4 + lq));
        f32x4 acc[4];
        #pragma unroll
        for (int mt = 0; mt < 4; ++mt) {
            f32x4 z = {0.f, 0.f, 0.f, 0.f};
            z = MFMA16(a1[2 * mt],     bb0, z);
            z = MFMA16(a1[2 * mt + 1], bb1, z);
            acc[mt] = z;
        }
        #pragma unroll
        for (int mt = 0; mt < 4; ++mt) {
            unsigned p0 = (unsigned)f2bf(fmaxf(acc[mt][0], 0.f)) |
                          ((unsigned)f2bf(fmaxf(acc[mt][1], 0.f)) << 16);
            unsigned p1 = (unsigned)f2bf(fmaxf(acc[mt][2], 0.f)) |
                          ((unsigned)f2bf(fmaxf(acc[mt][3], 0.f)) << 16);
            union { unsigned w[2]; uint2 v; } pk; pk.w[0] = p0; pk.w[1] = p1;
            *(uint2*)(yb + ybyte(px, 2 * mt + (lq >> 1)) + (lq & 1) * 8) = pk.v;
        }
    }

    // ---- L2: 64 <- 64, +b2, relu; h2 in place -------------------------------
    bf16x8 a2[8];
    #pragma unroll
    for (int f = 0; f < 8; ++f) a2[f] = __builtin_bit_cast(bf16x8, wf[(8 + f) * 64 + lane]);
    f32x4 b2v[4];
    #pragma unroll
    for (int mt = 0; mt < 4; ++mt)
        b2v[mt] = *(const f32x4*)(b2 + mt * 16 + lq * 4);

    #pragma unroll
    for (int nt = 0; nt < 4; ++nt) {
        const int px = px0 + nt * 16 + ln;
        bf16x8 bb0 = *(const bf16x8*)(yb + ybyte(px, lq));
        bf16x8 bb1 = *(const bf16x8*)(yb + ybyte(px, 4 + lq));
        f32x4 acc[4];
        #pragma unroll
        for (int mt = 0; mt < 4; ++mt) {
            f32x4 z = {0.f, 0.f, 0.f, 0.f};
            z = MFMA16(a2[2 * mt],     bb0, z);
            z = MFMA16(a2[2 * mt + 1], bb1, z);
            acc[mt] = z + b2v[mt];
        }
        #pragma unroll
        for (int mt = 0; mt < 4; ++mt) {
            unsigned p0 = (unsigned)f2bf(fmaxf(acc[mt][0], 0.f)) |
                          ((unsigned)f2bf(fmaxf(acc[mt][1], 0.f)) << 16);
            unsigned p1 = (unsigned)f2bf(fmaxf(acc[mt][2], 0.f)) |
                          ((unsigned)f2bf(fmaxf(acc[mt][3], 0.f)) << 16);
            union { unsigned w[2]; uint2 v; } pk; pk.w[0] = p0; pk.w[1] = p1;
            *(uint2*)(yb + ybyte(px, 2 * mt + (lq >> 1)) + (lq & 1) * 8) = pk.v;
        }
    }

    // ---- L3: 16 <- 64 + epilogue --------------------------------------------
    bf16x8 a3[2];
    a3[0] = __builtin_bit_cast(bf16x8, wf[16 * 64 + lane]);
    a3[1] = __builtin_bit_cast(bf16x8, wf[17 * 64 + lane]);

    #pragma unroll
    for (int nt = 0; nt < 4; ++nt) {
        const int px = px0 + nt * 16 + ln;
        float xcv[4];
        if constexpr (MASK_IN) {
            const ushort_t* xin = (const ushort_t*)xin_v;
            const float mm = mmid[px];
            #pragma unroll
            for (int r = 0; r < 4; ++r)
                xcv[r] = bf2f(xin[base + (size_t)(lq * 4 + r) * cs + (size_t)h * NW + px]) * mm;
        } else {
            const float* xin = (const float*)xin_v;
            #pragma unroll
            for (int r = 0; r < 4; ++r)
                xcv[r] = xin[base + (size_t)(lq * 4 + r) * cs + (size_t)h * NW + px];
        }
        bf16x8 bb0 = *(const bf16x8*)(yb + ybyte(px, lq));
        bf16x8 bb1 = *(const bf16x8*)(yb + ybyte(px, 4 + lq));
        f32x4 z = {0.f, 0.f, 0.f, 0.f};
        z = MFMA16(a3[0], bb0, z);
        z = MFMA16(a3[1], bb1, z);
        #pragma unroll
        for (int r = 0; r < 4; ++r) {
            const size_t o = base + (size_t)(lq * 4 + r) * cs + (size_t)h * NW + px;
            float val = xcv[r] + z[r] * umv[nt];
            if constexpr (OUT_BF16) ((ushort_t*)xout_v)[o] = f2bf(val);
            else                    ((float*)xout_v)[o]   = val;
        }
    }
}

// ---------------------------------------------------------------------------
// Kernel B: final post-alive on f32 xmid, apply pre*post. 4 px/thread.
// ---------------------------------------------------------------------------
__global__ __launch_bounds__(256) void nca_step_b(
    const float* __restrict__ xmid,
    const unsigned char* __restrict__ preb,
    float* __restrict__ xout)
{
    const int gid = blockIdx.x * 256 + threadIdx.x;     // over B*H*(W/4)
    const int b   = gid >> 14;
    const int rem = gid & 16383;
    const int h   = rem >> 6;
    const int px  = (rem & 63) << 2;

    const float* alpha = xmid + ((size_t)b * NC + 3) * NH * NW;
    float m0 = -1e30f, m1 = -1e30f, m2 = -1e30f, m3 = -1e30f;
    #pragma unroll
    for (int dy = -1; dy <= 1; ++dy) {
        const int row = (h + dy) & (NH - 1);
        const float* r = alpha + (size_t)row * NW;
        float4 mid4 = *(const float4*)(r + px);
        float lm = r[(px - 1) & (NW - 1)];
        float rm = r[(px + 4) & (NW - 1)];
        m0 = fmaxf(m0, fmaxf(fmaxf(lm, mid4.x), mid4.y));
        m1 = fmaxf(m1, fmaxf(fmaxf(mid4.x, mid4.y), mid4.z));
        m2 = fmaxf(m2, fmaxf(fmaxf(mid4.y, mid4.z), mid4.w));
        m3 = fmaxf(m3, fmaxf(fmaxf(mid4.z, mid4.w), rm));
    }
    const size_t pix = ((size_t)b * NH + h) * NW + px;
    const unsigned char* pr = preb + pix;
    float f0 = (m0 > ALIVE_THRESH && pr[0]) ? 1.0f : 0.0f;
    float f1 = (m1 > ALIVE_THRESH && pr[1]) ? 1.0f : 0.0f;
    float f2 = (m2 > ALIVE_THRESH && pr[2]) ? 1.0f : 0.0f;
    float f3 = (m3 > ALIVE_THRESH && pr[3]) ? 1.0f : 0.0f;

    #pragma unroll
    for (int c = 0; c < NC; ++c) {
        const size_t o = (((size_t)b * NC + c) * NH + h) * NW + px;
        float4 v = *(const float4*)(xmid + o);
        v.x *= f0; v.y *= f1; v.z *= f2; v.w *= f3;
        *(float4*)(xout + o) = v;
    }
}

// ---------------------------------------------------------------------------
extern "C" void kernel_launch(void* const* d_in, const int* in_sizes, int n_in,
                              void* d_out, int out_size, void* d_ws, size_t ws_size,
                              hipStream_t stream) {
    const float* x  = (const float*)d_in[0];
    const float* w1 = (const float*)d_in[1];
    const float* b1 = (const float*)d_in[2];
    const float* w2 = (const float*)d_in[3];
    const float* b2 = (const float*)d_in[4];
    const float* w3 = (const float*)d_in[5];
    const float* um = (const float*)d_in[6];
    const int steps = in_sizes[6] / (NB * NH * NW);

    const size_t npix  = (size_t)NB * NH * NW;
    const size_t nelem = (size_t)NB * NC * NH * NW;

    float* xmid2         = (float*)d_ws;                          // 32 MB
    unsigned char* prebA = (unsigned char*)(xmid2 + nelem);       // 512 KB
    unsigned char* prebB = prebA + npix;                          // 512 KB
    int4* wf             = (int4*)(prebB + npix);                 // 18 KB
    float* xout          = (float*)d_out;
    // bf16 intermediate states live inside d_out (fully overwritten at end)
    ushort_t* bfA        = (ushort_t*)d_out;                      // 16 MB
    ushort_t* bfB        = bfA + nelem;                           // 16 MB

    prep_weights<<<18, 64, 0, stream>>>(w1, b1, w2, w3, wf);

    dim3 grdA(NH, NB);
    const int grdB = (int)(npix / 4) / 256;

    const void* cur = x;
    unsigned char* preb_last = prebA;
    for (int i = 0; i < steps; ++i) {
        const bool first = (i == 0), last = (i == steps - 1);
        const float* um_i = um + (size_t)i * npix;
        unsigned char* pout = (i % 2 == 0) ? prebA : prebB;
        unsigned char* pin  = (i % 2 == 0) ? prebB : prebA;
        void* bf_next = (i % 2 == 0) ? (void*)bfA : (void*)bfB;

        if (first && last) {
            nca_step_a<false, false><<<grdA, 256, 0, stream>>>(
                cur, um_i, b2, wf, xmid2, nullptr, pout);
        } else if (first) {
            nca_step_a<false, true><<<grdA, 256, 0, stream>>>(
                cur, um_i, b2, wf, bf_next, nullptr, pout);
            cur = bf_next;
        } else if (last) {
            nca_step_a<true, false><<<grdA, 256, 0, stream>>>(
                cur, um_i, b2, wf, xmid2, pin, pout);
        } else {
            nca_step_a<true, true><<<grdA, 256, 0, stream>>>(
                cur, um_i, b2, wf, bf_next, pin, pout);
            cur = bf_next;
        }
        preb_last = pout;
    }

    nca_step_b<<<grdB, 256, 0, stream>>>(xmid2, preb_last, xout);
}

// Round 4
// 63.697 us; speedup vs baseline: 10.9467x; 1.2005x over previous
//
#include <hip/hip_runtime.h>
#include <hip/hip_bf16.h>

#define NB 8
#define NC 16
#define NH 256
#define NW 256
#define ALIVE_THRESH 0.1f
#define UPDATE_RATE 0.25f

typedef __attribute__((ext_vector_type(8))) short bf16x8;
typedef __attribute__((ext_vector_type(4))) float f32x4;
typedef unsigned short ushort_t;

#define MFMA16(a, b, c) __builtin_amdgcn_mfma_f32_16x16x32_bf16((a), (b), (c), 0, 0, 0)

static __device__ __forceinline__ unsigned short f2bf(float f) {
    __hip_bfloat16 h = __float2bfloat16(f);          // RNE, compiler emits v_cvt_pk
    return __builtin_bit_cast(unsigned short, h);
}
static __device__ __forceinline__ float bf2f(unsigned short b) {
    union { unsigned u; float f; } x; x.u = ((unsigned)b) << 16; return x.f;
}
static __device__ __forceinline__ unsigned pack2(float lo, float hi) {
    return (unsigned)f2bf(lo) | ((unsigned)f2bf(hi) << 16);
}

// swizzled byte offset into the [256 px][64 bf16] activation buffer
static __device__ __forceinline__ int ybyte(int px, int g) {
    return px * 128 + ((g ^ (px & 7)) << 4);
}

// ---------------------------------------------------------------------------
// Pre-kernel: pack W1(+b1 as k=48 row), W2, W3 into MFMA A-fragment order.
// ---------------------------------------------------------------------------
__global__ void prep_weights(const float* __restrict__ w1, const float* __restrict__ b1,
                             const float* __restrict__ w2, const float* __restrict__ w3,
                             int4* __restrict__ wf)
{
    const int f = blockIdx.x, l = threadIdx.x;
    const int lq = l >> 4, ln = l & 15;
    union { unsigned short us[8]; int4 v; } u;
    if (f < 8) {
        const int mt = f >> 1, ks = f & 1, m = mt * 16 + ln;
        #pragma unroll
        for (int j = 0; j < 8; ++j) {
            const int k = ks * 32 + lq * 8 + j;
            float v = (k < 48) ? w1[m * 48 + k] : ((k == 48) ? b1[m] : 0.0f);
            u.us[j] = f2bf(v);
        }
    } else if (f < 16) {
        const int ff = f - 8, mt = ff >> 1, ks = ff & 1, m = mt * 16 + ln;
        #pragma unroll
        for (int j = 0; j < 8; ++j)
            u.us[j] = f2bf(w2[m * 64 + (ks * 32 + lq * 8 + j)]);
    } else {
        const int ks = f - 16, m = ln;
        #pragma unroll
        for (int j = 0; j < 8; ++j)
            u.us[j] = f2bf(w3[m * 64 + (ks * 32 + lq * 8 + j)]);
    }
    wf[f * 64 + l] = u.v;
}

// ---------------------------------------------------------------------------
// Kernel A: one block = one image row (b,h). 4 waves. Output always bf16
// (unmasked updated state) + pre-alive byte mask of THIS step.
// MASK_IN:  input is bf16 unmasked state of previous step; apply pre*post on
//           the fly (5-row alpha window).
// !MASK_IN: input is f32 initial state.
// LDS: ybuf 32KB; sd (16KB) overlaid at ybuf+4KB; vbuf (3KB) at ybuf+0.
// ---------------------------------------------------------------------------
template<bool MASK_IN>
__global__ __launch_bounds__(256) void nca_step_a(
    const void* __restrict__ xin_v,
    const float* __restrict__ um,      // offset to this step: (B,1,H,W)
    const float* __restrict__ b2,
    const int4*  __restrict__ wf,
    ushort_t* __restrict__ xout,       // bf16 unmasked updated state
    const unsigned char* __restrict__ preb_in,
    unsigned char* __restrict__ preb_out)
{
    __shared__ char  smem[256 * 128];   // 32 KB: ybuf / sd / vbuf overlays
    __shared__ float premax2[NW];       // 1 KB
    __shared__ float mmid[NW];          // 1 KB (MASK_IN only)

    char*     yb   = smem;
    unsigned* sd   = (unsigned*)(smem + 4096);   // [NC][NW] packed bf16 s|d
    float*    vbuf = (float*)smem;               // [3][NW] (MASK_IN only)

    const int t = threadIdx.x;
    const int bx = blockIdx.x;
    const int h = ((bx & 7) << 5) | (bx >> 3);   // XCD-chunked row swizzle
    const int b = blockIdx.y;
    const int hm = (h - 1) & (NH - 1), hp = (h + 1) & (NH - 1);
    const size_t cs = (size_t)NH * NW;
    const size_t base = (size_t)b * NC * cs;

    float mreg[NC], dreg[NC];

    if constexpr (MASK_IN) {
        const ushort_t* xin = (const ushort_t*)xin_v;
        const ushort_t* ac = xin + base + 3 * cs;
        float am[5];
        #pragma unroll
        for (int j = 0; j < 5; ++j)
            am[j] = bf2f(ac[(size_t)((h - 2 + j) & (NH - 1)) * NW + t]);
        vbuf[0 * NW + t] = fmaxf(fmaxf(am[0], am[1]), am[2]);
        vbuf[1 * NW + t] = fmaxf(fmaxf(am[1], am[2]), am[3]);
        vbuf[2 * NW + t] = fmaxf(fmaxf(am[2], am[3]), am[4]);
        const unsigned char p0 = preb_in[((size_t)b * NH + hm) * NW + t];
        const unsigned char p1 = preb_in[((size_t)b * NH + h ) * NW + t];
        const unsigned char p2 = preb_in[((size_t)b * NH + hp) * NW + t];
        __syncthreads();                                    // B1: vbuf ready

        const int tm = (t - 1) & (NW - 1), tp = (t + 1) & (NW - 1);
        float x0 = fmaxf(fmaxf(vbuf[tm],          vbuf[t]),          vbuf[tp]);
        float x1 = fmaxf(fmaxf(vbuf[NW + tm],     vbuf[NW + t]),     vbuf[NW + tp]);
        float x2 = fmaxf(fmaxf(vbuf[2 * NW + tm], vbuf[2 * NW + t]), vbuf[2 * NW + tp]);
        const float m0 = (x0 > ALIVE_THRESH && p0) ? 1.0f : 0.0f;
        const float m1 = (x1 > ALIVE_THRESH && p1) ? 1.0f : 0.0f;
        const float m2 = (x2 > ALIVE_THRESH && p2) ? 1.0f : 0.0f;
        mmid[t] = m1;
        premax2[t] = fmaxf(fmaxf(am[1] * m0, am[2] * m1), am[3] * m2);

        // sd region (smem+4KB..) is disjoint from vbuf (0..3KB): safe to
        // write while other threads still read vbuf.
        #pragma unroll
        for (int c = 0; c < NC; ++c) {
            float top, mid, bot;
            if (c == 3) { top = am[1] * m0; mid = am[2] * m1; bot = am[3] * m2; }
            else {
                const ushort_t* xc = xin + base + (size_t)c * cs;
                top = bf2f(xc[(size_t)hm * NW + t]) * m0;
                mid = bf2f(xc[(size_t)h  * NW + t]) * m1;
                bot = bf2f(xc[(size_t)hp * NW + t]) * m2;
            }
            float s = top + 2.0f * mid + bot, d = bot - top;
            sd[c * NW + t] = pack2(s, d);
            mreg[c] = mid; dreg[c] = d;
        }
        __syncthreads();                                    // B2: sd ready
    } else {
        const float* xin = (const float*)xin_v;
        #pragma unroll
        for (int c = 0; c < NC; ++c) {
            const float* xc = xin + base + (size_t)c * cs;
            float top = xc[(size_t)hm * NW + t];
            float mid = xc[(size_t)h  * NW + t];
            float bot = xc[(size_t)hp * NW + t];
            float s = top + 2.0f * mid + bot, d = bot - top;
            sd[c * NW + t] = pack2(s, d);
            mreg[c] = mid; dreg[c] = d;
            if (c == 3) premax2[t] = fmaxf(fmaxf(top, mid), bot);
        }
        __syncthreads();                                    // B2: sd ready
    }

    // ---- pre mask of THIS step --------------------------------------------
    {
        const int tm = (t - 1) & (NW - 1), tp = (t + 1) & (NW - 1);
        float mx = fmaxf(fmaxf(premax2[tm], premax2[t]), premax2[tp]);
        preb_out[((size_t)b * NH + h) * NW + t] = (mx > ALIVE_THRESH) ? 1 : 0;
    }

    // ---- phase 2: horizontal combine -> y[48] (registers) ------------------
    unsigned yp[24];
    {
        const int tm = (t - 1) & (NW - 1), tp = (t + 1) & (NW - 1);
        #pragma unroll
        for (int c = 0; c < NC; ++c) {
            unsigned L = sd[c * NW + tm];
            unsigned R = sd[c * NW + tp];
            float sl = bf2f((unsigned short)L), dl = bf2f((unsigned short)(L >> 16));
            float sr = bf2f((unsigned short)R), dr = bf2f((unsigned short)(R >> 16));
            float y0 = mreg[c];                       // ident
            float y1 = sr - sl;                       // sobel_x
            float y2 = dl + 2.0f * dreg[c] + dr;      // sobel_y
            unsigned short u0 = f2bf(y0), u1 = f2bf(y1), u2 = f2bf(y2);
            const int k = 3 * c;                      // even: c even -> aligned
            if ((k & 1) == 0) {
                yp[k >> 1] = (unsigned)u0 | ((unsigned)u1 << 16);
                if (((k + 2) & 1) == 0) yp[(k + 2) >> 1] = (unsigned)u2;
                else                    yp[(k + 2) >> 1] |= 0; // unreachable
            } else {
                yp[k >> 1] |= ((unsigned)u0 << 16);
                yp[(k + 1) >> 1] = (unsigned)u1 | ((unsigned)u2 << 16);
            }
            // note: k=3c alternates even/odd; both branches above fill
            // exactly 3 half-words; the pattern below re-derives cleanly.
        }
        // The above branchy fill is fragile; rebuild deterministically:
        // (compiler folds this — values recomputed into a clean pack)
    }
    {
        // deterministic re-pack (overwrites yp fully)
        const int tm = (t - 1) & (NW - 1), tp = (t + 1) & (NW - 1);
        unsigned short ys[48];
        #pragma unroll
        for (int c = 0; c < NC; ++c) {
            unsigned L = sd[c * NW + tm];
            unsigned R = sd[c * NW + tp];
            float sl = bf2f((unsigned short)L), dl = bf2f((unsigned short)(L >> 16));
            float sr = bf2f((unsigned short)R), dr = bf2f((unsigned short)(R >> 16));
            ys[3 * c + 0] = f2bf(mreg[c]);
            ys[3 * c + 1] = f2bf(sr - sl);
            ys[3 * c + 2] = f2bf(dl + 2.0f * dreg[c] + dr);
        }
        #pragma unroll
        for (int i = 0; i < 24; ++i)
            yp[i] = (unsigned)ys[2 * i] | ((unsigned)ys[2 * i + 1] << 16);
    }
    __syncthreads();                                        // B3: sd reads done

    {
        #pragma unroll
        for (int g = 0; g < 6; ++g) {
            union { unsigned w[4]; int4 v; } pk;
            pk.w[0] = yp[4 * g]; pk.w[1] = yp[4 * g + 1];
            pk.w[2] = yp[4 * g + 2]; pk.w[3] = yp[4 * g + 3];
            *(int4*)(yb + ybyte(t, g)) = pk.v;
        }
        int4 biasrow; biasrow.x = 0x3F80; biasrow.y = 0; biasrow.z = 0; biasrow.w = 0;
        *(int4*)(yb + ybyte(t, 6)) = biasrow;         // k=48 -> 1.0 (bias)
        int4 zz; zz.x = zz.y = zz.z = zz.w = 0;
        *(int4*)(yb + ybyte(t, 7)) = zz;
    }
    // No barrier: each wave's MFMA B-reads only touch px rows written by its
    // own lanes (in-order intra-wave LDS).

    // ---- phase 3: GEMMs -----------------------------------------------------
    const int lane = t & 63, wv = t >> 6;
    const int lq = lane >> 4, ln = lane & 15;
    const int px0 = wv * 64;

    float umv[4];
    {
        const float* umr = um + ((size_t)b * NH + h) * NW;
        #pragma unroll
        for (int nt = 0; nt < 4; ++nt)
            umv[nt] = (umr[px0 + nt * 16 + ln] < UPDATE_RATE) ? 1.0f : 0.0f;
    }

    // ---- L1: 64 <- 48(+bias), relu; h1 in place ----------------------------
    bf16x8 a1[8];
    #pragma unroll
    for (int f = 0; f < 8; ++f) a1[f] = __builtin_bit_cast(bf16x8, wf[f * 64 + lane]);

    #pragma unroll
    for (int nt = 0; nt < 4; ++nt) {
        const int px = px0 + nt * 16 + ln;
        bf16x8 bb0 = *(const bf16x8*)(yb + ybyte(px, lq));
        bf16x8 bb1 = *(const bf16x8*)(yb + ybyte(px, 4 + lq));
        f32x4 acc[4];
        #pragma unroll
        for (int mt = 0; mt < 4; ++mt) {
            f32x4 z = {0.f, 0.f, 0.f, 0.f};
            z = MFMA16(a1[2 * mt],     bb0, z);
            z = MFMA16(a1[2 * mt + 1], bb1, z);
            acc[mt] = z;
        }
        #pragma unroll
        for (int mt = 0; mt < 4; ++mt) {
            unsigned p0 = pack2(fmaxf(acc[mt][0], 0.f), fmaxf(acc[mt][1], 0.f));
            unsigned p1 = pack2(fmaxf(acc[mt][2], 0.f), fmaxf(acc[mt][3], 0.f));
            union { unsigned w[2]; uint2 v; } pk; pk.w[0] = p0; pk.w[1] = p1;
            *(uint2*)(yb + ybyte(px, 2 * mt + (lq >> 1)) + (lq & 1) * 8) = pk.v;
        }
    }

    // ---- L2: 64 <- 64, +b2, relu; h2 in place -------------------------------
    bf16x8 a2[8];
    #pragma unroll
    for (int f = 0; f < 8; ++f) a2[f] = __builtin_bit_cast(bf16x8, wf[(8 + f) * 64 + lane]);
    f32x4 b2v[4];
    #pragma unroll
    for (int mt = 0; mt < 4; ++mt)
        b2v[mt] = *(const f32x4*)(b2 + mt * 16 + lq * 4);

    #pragma unroll
    for (int nt = 0; nt < 4; ++nt) {
        const int px = px0 + nt * 16 + ln;
        bf16x8 bb0 = *(const bf16x8*)(yb + ybyte(px, lq));
        bf16x8 bb1 = *(const bf16x8*)(yb + ybyte(px, 4 + lq));
        f32x4 acc[4];
        #pragma unroll
        for (int mt = 0; mt < 4; ++mt) {
            f32x4 z = {0.f, 0.f, 0.f, 0.f};
            z = MFMA16(a2[2 * mt],     bb0, z);
            z = MFMA16(a2[2 * mt + 1], bb1, z);
            acc[mt] = z + b2v[mt];
        }
        #pragma unroll
        for (int mt = 0; mt < 4; ++mt) {
            unsigned p0 = pack2(fmaxf(acc[mt][0], 0.f), fmaxf(acc[mt][1], 0.f));
            unsigned p1 = pack2(fmaxf(acc[mt][2], 0.f), fmaxf(acc[mt][3], 0.f));
            union { unsigned w[2]; uint2 v; } pk; pk.w[0] = p0; pk.w[1] = p1;
            *(uint2*)(yb + ybyte(px, 2 * mt + (lq >> 1)) + (lq & 1) * 8) = pk.v;
        }
    }

    // ---- L3: 16 <- 64 + epilogue (bf16 out) ---------------------------------
    bf16x8 a3[2];
    a3[0] = __builtin_bit_cast(bf16x8, wf[16 * 64 + lane]);
    a3[1] = __builtin_bit_cast(bf16x8, wf[17 * 64 + lane]);

    #pragma unroll
    for (int nt = 0; nt < 4; ++nt) {
        const int px = px0 + nt * 16 + ln;
        float xcv[4];
        if constexpr (MASK_IN) {
            const ushort_t* xin = (const ushort_t*)xin_v;
            const float mm = mmid[px];
            #pragma unroll
            for (int r = 0; r < 4; ++r)
                xcv[r] = bf2f(xin[base + (size_t)(lq * 4 + r) * cs + (size_t)h * NW + px]) * mm;
        } else {
            const float* xin = (const float*)xin_v;
            #pragma unroll
            for (int r = 0; r < 4; ++r)
                xcv[r] = xin[base + (size_t)(lq * 4 + r) * cs + (size_t)h * NW + px];
        }
        bf16x8 bb0 = *(const bf16x8*)(yb + ybyte(px, lq));
        bf16x8 bb1 = *(const bf16x8*)(yb + ybyte(px, 4 + lq));
        f32x4 z = {0.f, 0.f, 0.f, 0.f};
        z = MFMA16(a3[0], bb0, z);
        z = MFMA16(a3[1], bb1, z);
        #pragma unroll
        for (int r = 0; r < 4; ++r) {
            const size_t o = base + (size_t)(lq * 4 + r) * cs + (size_t)h * NW + px;
            xout[o] = f2bf(xcv[r] + z[r] * umv[nt]);
        }
    }
}

// ---------------------------------------------------------------------------
// Final kernel: post-alive on bf16 state, apply pre*post, write f32 output.
// ---------------------------------------------------------------------------
__global__ __launch_bounds__(256) void nca_final(
    const ushort_t* __restrict__ bf,
    const unsigned char* __restrict__ preb,
    float* __restrict__ xout)
{
    __shared__ float vmax[NW];

    const int t = threadIdx.x;
    const int bx = blockIdx.x;
    const int h = ((bx & 7) << 5) | (bx >> 3);
    const int b = blockIdx.y;
    const int hm = (h - 1) & (NH - 1), hp = (h + 1) & (NH - 1);
    const size_t cs = (size_t)NH * NW;
    const size_t base = (size_t)b * NC * cs;

    const ushort_t* ac = bf + base + 3 * cs;
    float a0 = bf2f(ac[(size_t)hm * NW + t]);
    float a1 = bf2f(ac[(size_t)h  * NW + t]);
    float a2 = bf2f(ac[(size_t)hp * NW + t]);
    vmax[t] = fmaxf(fmaxf(a0, a1), a2);
    const unsigned char p = preb[((size_t)b * NH + h) * NW + t];
    __syncthreads();

    const int tm = (t - 1) & (NW - 1), tp = (t + 1) & (NW - 1);
    float mx = fmaxf(fmaxf(vmax[tm], vmax[t]), vmax[tp]);
    const float m = (mx > ALIVE_THRESH && p) ? 1.0f : 0.0f;

    #pragma unroll
    for (int c = 0; c < NC; ++c) {
        const size_t o = base + (size_t)c * cs + (size_t)h * NW + t;
        xout[o] = bf2f(bf[o]) * m;
    }
}

// ---------------------------------------------------------------------------
extern "C" void kernel_launch(void* const* d_in, const int* in_sizes, int n_in,
                              void* d_out, int out_size, void* d_ws, size_t ws_size,
                              hipStream_t stream) {
    const float* x  = (const float*)d_in[0];
    const float* w1 = (const float*)d_in[1];
    const float* b1 = (const float*)d_in[2];
    const float* w2 = (const float*)d_in[3];
    const float* b2 = (const float*)d_in[4];
    const float* w3 = (const float*)d_in[5];
    const float* um = (const float*)d_in[6];
    const int steps = in_sizes[6] / (NB * NH * NW);

    const size_t npix  = (size_t)NB * NH * NW;
    const size_t nelem = (size_t)NB * NC * NH * NW;

    ushort_t* bfA        = (ushort_t*)d_ws;                 // 16 MB
    ushort_t* bfB        = bfA + nelem;                     // 16 MB
    unsigned char* prebA = (unsigned char*)(bfB + nelem);   // 512 KB
    unsigned char* prebB = prebA + npix;                    // 512 KB
    int4* wf             = (int4*)(prebB + npix);           // 18 KB
    float* xout          = (float*)d_out;

    prep_weights<<<18, 64, 0, stream>>>(w1, b1, w2, w3, wf);

    dim3 grdA(NH, NB);

    const void* cur = x;
    unsigned char* preb_last = prebA;
    for (int i = 0; i < steps; ++i) {
        const float* um_i = um + (size_t)i * npix;
        ushort_t* bfo      = (i % 2 == 0) ? bfA : bfB;
        unsigned char* po  = (i % 2 == 0) ? prebA : prebB;
        unsigned char* pin = (i % 2 == 0) ? prebB : prebA;

        if (i == 0)
            nca_step_a<false><<<grdA, 256, 0, stream>>>(
                cur, um_i, b2, wf, bfo, nullptr, po);
        else
            nca_step_a<true><<<grdA, 256, 0, stream>>>(
                cur, um_i, b2, wf, bfo, pin, po);
        cur = bfo;
        preb_last = po;
    }

    nca_final<<<grdA, 256, 0, stream>>>((const ushort_t*)cur, preb_last, xout);
}